// Round 20
// baseline (301.484 us; speedup 1.0000x reference)
//
#include <hip/hip_runtime.h>
#include <math.h>

typedef short short8 __attribute__((ext_vector_type(8)));
typedef float f32x4 __attribute__((ext_vector_type(4)));

static constexpr float SCALE = 0.17677669529663687f; // 32^-0.5

__device__ __forceinline__ ushort f2bf(float x) {
    uint u = __float_as_uint(x);
    u += 0x7fff + ((u >> 16) & 1);
    return (ushort)(u >> 16);
}
__device__ __forceinline__ ushort4 cvt4(float4 v) {
    return make_ushort4(f2bf(v.x), f2bf(v.y), f2bf(v.z), f2bf(v.w));
}

__device__ __forceinline__ const float* row_src(
    int bb, int tok, const float* __restrict__ x, const float* __restrict__ gt)
{
    if (tok < 8) return gt + tok * 256;
    int j = tok - 8;
    int wn = bb & 7, hn = (bb >> 3) & 7, tn = (bb >> 6) & 1, b = bb >> 7;
    int cw = j & 7, ch = (j >> 3) & 7, ct = j >> 6;
    return x + ((((size_t)(b * 8 + tn * 4 + ct)) * 64 + (hn * 8 + ch)) * 64
                + (wn * 8 + cw)) * 256;
}

union F8 { ushort4 q[2]; short8 v; };

// ---------------- K0: transpose weights to [n][k] bf16 ----------------
__global__ __launch_bounds__(256)
void k_prep(const float* __restrict__ Wq, const float* __restrict__ Wo,
            ushort* __restrict__ WqtH, ushort* __restrict__ WotH)
{
    int i = blockIdx.x * 256 + threadIdx.x;
    if (i < 196608) {
        uint k = (uint)i / 768u, n = (uint)i - k * 768u;
        WqtH[n * 256 + k] = f2bf(Wq[i]);
    } else {
        int j = i - 196608;
        uint k = (uint)j >> 8, n = (uint)j & 255u;
        WotH[n * 256 + k] = f2bf(Wo[j]);
    }
}

// ---- K1: QKV GEMM — BK=64 (8 barriers), r18 ping-pong schedule -------------
// 2-deep sets; pure ds_write between barriers; cvt after the MFMA block.
// LDS 34.8 KB -> still 4 blocks/CU. Layout/epilogue unchanged from r19.
#define GP 36    // k_out / epilogue stride (unchanged)
#define GQ 68    // k_qkv BK=64 row stride in ushorts (136 B, 2-way max alias)
__global__ __launch_bounds__(256, 4)
void k_qkv(const float* __restrict__ x, const ushort* __restrict__ WtH,
           const float* __restrict__ gt, ushort* __restrict__ qkv,
           int nb, int bb0, int mrows)
{
    int g = blockIdx.x;
    int xcd = g & 7;
    int j6 = g >> 3;
    int m_t = (j6 / 6) * 8 + xcd;
    int n_t = j6 % 6;
    if (m_t >= nb) return;
    const int m0 = m_t * 128, n0 = n_t * 128;

    __shared__ ushort SM[2 * 128 * GQ];   // Ah | Bh (34.8 KB); Tr reuses front
    ushort* Ah = SM;
    ushort* Bh = SM + 128 * GQ;
    const int tid = threadIdx.x;
    const int lane = tid & 63, wid = tid >> 6;
    const int ln = lane & 15, lg = lane >> 4;
    const int wm = wid >> 1, wn = wid & 1;

    const int srow = tid >> 1;
    const int kh = (tid & 1) * 32;       // each thread stages 32 k-elems
    int mst = m0 + srow;
    if (mst >= mrows) mst = mrows - 1;
    int lb = mst / 264, tok = mst - lb * 264;
    const float* rsrc = row_src(bb0 + lb, tok, x, gt) + kh;
    const ushort* bsrcH = WtH + (size_t)(n0 + srow) * 256 + kh;

    f32x4 acc[4][4];
#pragma unroll
    for (int i = 0; i < 4; ++i)
#pragma unroll
        for (int j = 0; j < 4; ++j) acc[i][j] = (f32x4){0.f, 0.f, 0.f, 0.f};

    // prologue: tiles 0 and 1 (BK=64 each) pre-converted into ping-pong sets
    ushort4 aset[2][8], bset[2][8];
#pragma unroll
    for (int j = 0; j < 8; ++j) {
        aset[0][j] = cvt4(*(const float4*)(rsrc + 4 * j));
        bset[0][j] = *(const ushort4*)(bsrcH + 4 * j);
        aset[1][j] = cvt4(*(const float4*)(rsrc + 64 + 4 * j));
        bset[1][j] = *(const ushort4*)(bsrcH + 64 + 4 * j);
    }

#pragma unroll
    for (int it = 0; it < 4; ++it) {
        const int s = it & 1;
        __syncthreads();
        // pure ds_write staging (no waits/VALU in the barrier-locked section)
#pragma unroll
        for (int j = 0; j < 8; ++j) {
            *(ushort4*)&Ah[srow * GQ + kh + 4 * j] = aset[s][j];
            *(ushort4*)&Bh[srow * GQ + kh + 4 * j] = bset[s][j];
        }
        __syncthreads();

        // issue loads for tile it+2; waits land after the MFMA blocks
        float4 ta[8];
        ushort4 tb[8];
        const bool more = (it + 2 < 4);
        if (more) {
            const int ktn = 64 * (it + 2);
#pragma unroll
            for (int j = 0; j < 8; ++j) {
                ta[j] = *(const float4*)(rsrc + ktn + 4 * j);
                tb[j] = *(const ushort4*)(bsrcH + ktn + 4 * j);
            }
        }

        // two k-halves processed sequentially (caps live fragment registers)
#pragma unroll
        for (int h2 = 0; h2 < 2; ++h2) {
            const int ko = h2 * 32;
            short8 af[4], bf[4];
#pragma unroll
            for (int mi = 0; mi < 4; ++mi) {
                int base = (wm * 64 + mi * 16 + ln) * GQ + ko + 4 * lg;
                F8 t;
                t.q[0] = *(const ushort4*)&Ah[base]; t.q[1] = *(const ushort4*)&Ah[base + 16];
                af[mi] = t.v;
            }
#pragma unroll
            for (int ni = 0; ni < 4; ++ni) {
                int base = (wn * 64 + ni * 16 + ln) * GQ + ko + 4 * lg;
                F8 t;
                t.q[0] = *(const ushort4*)&Bh[base]; t.q[1] = *(const ushort4*)&Bh[base + 16];
                bf[ni] = t.v;
            }
#pragma unroll
            for (int mi = 0; mi < 4; ++mi)
#pragma unroll
                for (int ni = 0; ni < 4; ++ni)
                    acc[mi][ni] = __builtin_amdgcn_mfma_f32_16x16x32_bf16(af[mi], bf[ni], acc[mi][ni], 0, 0, 0);
        }

        // convert after MFMAs (vmcnt waits overlapped the compute above)
        if (more) {
#pragma unroll
            for (int j = 0; j < 8; ++j) {
                aset[s][j] = cvt4(ta[j]);
                bset[s][j] = tb[j];
            }
        }
    }

    // ---- epilogue: LDS transpose -> bf16 full-128B-line stores (unchanged) --
    float* Tr = (float*)SM;              // 32 x 132 fp32 = 16.9 KB (fits 34.8)
    const int trow = tid >> 3;
    const int t8 = (tid & 7) * 8;
#pragma unroll
    for (int mi = 0; mi < 4; ++mi) {
        __syncthreads();
#pragma unroll
        for (int ni = 0; ni < 4; ++ni)
#pragma unroll
            for (int r = 0; r < 4; ++r)
                Tr[(wm * 16 + lg * 4 + r) * 132 + wn * 64 + ni * 16 + ln] = acc[mi][ni][r];
        __syncthreads();
        int gm = m0 + (trow >> 4) * 64 + mi * 16 + (trow & 15);
        if (gm < mrows) {
            ushort* dst = qkv + (size_t)gm * 768 + n0;
            const float* src = &Tr[trow * 132];
#pragma unroll
            for (int half = 0; half < 2; ++half) {
                float4 a = *(const float4*)(src + half * 64 + t8);
                float4 b = *(const float4*)(src + half * 64 + t8 + 4);
                union { ushort4 u4[2]; int4 i4; } pk;
                pk.u4[0] = cvt4(a);
                pk.u4[1] = cvt4(b);
                *(int4*)(dst + half * 64 + t8) = pk.i4;
            }
        }
    }
}

// ---- K2: attention — swapped-operand MFMA, bf16 qkv, NO-MAX softmax --------
#define KPAD 36
#define VPAD 296
__global__ __launch_bounds__(256, 4)
void k_attn(ushort* __restrict__ qkv)
{
    __shared__ ushort Khi[272 * KPAD];
    __shared__ ushort Vt[32 * VPAD];

    const int lb = blockIdx.x, h = blockIdx.y;
    const int tid = threadIdx.x;
    const int wid = tid >> 6;
    const int lane = tid & 63;
    const int ln = lane & 15, lg = lane >> 4;
    ushort* base = qkv + (size_t)lb * (264 * 768);
    const int koff = 256 + h * 32, voff = 512 + h * 32;

    for (int slot = tid; slot < 1056; slot += 256) {
        int rp = slot >> 3;
        int c4 = (slot & 7) * 4;
        int r0 = rp * 2;
        const ushort* p0 = base + (size_t)r0 * 768;
        const ushort* p1 = p0 + 768;
        ushort4 k0 = *(const ushort4*)(p0 + koff + c4);
        ushort4 k1 = *(const ushort4*)(p1 + koff + c4);
        ushort4 v0 = *(const ushort4*)(p0 + voff + c4);
        ushort4 v1 = *(const ushort4*)(p1 + voff + c4);
        *(ushort4*)&Khi[r0 * KPAD + c4] = k0;
        *(ushort4*)&Khi[(r0 + 1) * KPAD + c4] = k1;
        *(ushort2*)&Vt[(c4 + 0) * VPAD + r0] = make_ushort2(v0.x, v1.x);
        *(ushort2*)&Vt[(c4 + 1) * VPAD + r0] = make_ushort2(v0.y, v1.y);
        *(ushort2*)&Vt[(c4 + 2) * VPAD + r0] = make_ushort2(v0.z, v1.z);
        *(ushort2*)&Vt[(c4 + 3) * VPAD + r0] = make_ushort2(v0.w, v1.w);
    }
    for (int slot = tid; slot < 1024; slot += 256) {
        int d = slot >> 5;
        Vt[d * VPAD + 264 + (slot & 31)] = 0;
    }

    short8 qh[4];
#pragma unroll
    for (int t = 0; t < 4; ++t) {
        int qrow = 8 + (wid * 4 + t) * 16 + ln;
        const ushort* qp = base + (size_t)qrow * 768 + h * 32;
        F8 fh;
        fh.q[0] = *(const ushort4*)(qp + 4 * lg);
        fh.q[1] = *(const ushort4*)(qp + 16 + 4 * lg);
        qh[t] = fh.v;
    }

    f32x4 acc[4][2];
    float lsum[4];
#pragma unroll
    for (int t = 0; t < 4; ++t) {
        acc[t][0] = (f32x4){0.f, 0.f, 0.f, 0.f};
        acc[t][1] = (f32x4){0.f, 0.f, 0.f, 0.f};
        lsum[t] = 0.f;
    }

    __syncthreads();

    for (int g = 0; g < 8; ++g) {
        const int kt0 = g * 32;
        F8 fa;
        const ushort* pka = &Khi[(kt0 + ln) * KPAD + 4 * lg];
        fa.q[0] = *(const ushort4*)pka; fa.q[1] = *(const ushort4*)(pka + 16);
        short8 ka = fa.v;
        const ushort* pkb = &Khi[(kt0 + 16 + ln) * KPAD + 4 * lg];
        fa.q[0] = *(const ushort4*)pkb; fa.q[1] = *(const ushort4*)(pkb + 16);
        short8 kb = fa.v;
        const ushort* pv0 = &Vt[ln * VPAD + kt0 + 4 * lg];
        fa.q[0] = *(const ushort4*)pv0; fa.q[1] = *(const ushort4*)(pv0 + 16);
        short8 va = fa.v;
        const ushort* pv1 = &Vt[(16 + ln) * VPAD + kt0 + 4 * lg];
        fa.q[0] = *(const ushort4*)pv1; fa.q[1] = *(const ushort4*)(pv1 + 16);
        short8 vb = fa.v;

#pragma unroll
        for (int t = 0; t < 4; ++t) {
            f32x4 sa = {0.f, 0.f, 0.f, 0.f}, sb = {0.f, 0.f, 0.f, 0.f};
            sa = __builtin_amdgcn_mfma_f32_16x16x32_bf16(ka, qh[t], sa, 0, 0, 0);
            sb = __builtin_amdgcn_mfma_f32_16x16x32_bf16(kb, qh[t], sb, 0, 0, 0);
            float p[8];
#pragma unroll
            for (int c = 0; c < 4; ++c) {
                p[c] = __expf(sa[c] * SCALE);
                p[4 + c] = __expf(sb[c] * SCALE);
            }
            lsum[t] += ((p[0] + p[1]) + (p[2] + p[3])) + ((p[4] + p[5]) + (p[6] + p[7]));
            F8 pf;
            pf.q[0] = make_ushort4(f2bf(p[0]), f2bf(p[1]), f2bf(p[2]), f2bf(p[3]));
            pf.q[1] = make_ushort4(f2bf(p[4]), f2bf(p[5]), f2bf(p[6]), f2bf(p[7]));
            acc[t][0] = __builtin_amdgcn_mfma_f32_16x16x32_bf16(va, pf.v, acc[t][0], 0, 0, 0);
            acc[t][1] = __builtin_amdgcn_mfma_f32_16x16x32_bf16(vb, pf.v, acc[t][1], 0, 0, 0);
        }
    }

    // ---- tail: keys 256..263 (rows >= 8 of the tile masked via lg>=2) ----
    {
        F8 fa;
        const ushort* pka = &Khi[(256 + ln) * KPAD + 4 * lg];
        fa.q[0] = *(const ushort4*)pka; fa.q[1] = *(const ushort4*)(pka + 16);
        short8 ka = fa.v;
        const ushort* pv0 = &Vt[ln * VPAD + 256 + 4 * lg];
        fa.q[0] = *(const ushort4*)pv0; fa.q[1] = *(const ushort4*)(pv0 + 16);
        short8 va = fa.v;
        const ushort* pv1 = &Vt[(16 + ln) * VPAD + 256 + 4 * lg];
        fa.q[0] = *(const ushort4*)pv1; fa.q[1] = *(const ushort4*)(pv1 + 16);
        short8 vb = fa.v;

#pragma unroll
        for (int t = 0; t < 4; ++t) {
            f32x4 sa = {0.f, 0.f, 0.f, 0.f};
            sa = __builtin_amdgcn_mfma_f32_16x16x32_bf16(ka, qh[t], sa, 0, 0, 0);
            float p[4];
#pragma unroll
            for (int c = 0; c < 4; ++c)
                p[c] = (lg >= 2) ? 0.f : __expf(sa[c] * SCALE);
            lsum[t] += (p[0] + p[1]) + (p[2] + p[3]);
            F8 pf;
            pf.q[0] = make_ushort4(f2bf(p[0]), f2bf(p[1]), f2bf(p[2]), f2bf(p[3]));
            pf.q[1] = make_ushort4(0, 0, 0, 0);
            acc[t][0] = __builtin_amdgcn_mfma_f32_16x16x32_bf16(va, pf.v, acc[t][0], 0, 0, 0);
            acc[t][1] = __builtin_amdgcn_mfma_f32_16x16x32_bf16(vb, pf.v, acc[t][1], 0, 0, 0);
        }
    }

#pragma unroll
    for (int t = 0; t < 4; ++t) {
        float l = lsum[t];
        l += __shfl_xor(l, 16);
        l += __shfl_xor(l, 32);
        float inv = 1.f / l;
        ushort* op = base + (size_t)(8 + (wid * 4 + t) * 16 + ln) * 768 + h * 32;
#pragma unroll
        for (int r = 0; r < 4; ++r) {
            op[lg * 4 + r] = f2bf(acc[t][0][r] * inv);
            op[16 + lg * 4 + r] = f2bf(acc[t][1][r] * inv);
        }
    }
}

// ---- K3: output GEMM (bf16 in, simple 2-phase prefetch — r19 form) ---------
__global__ __launch_bounds__(256, 4)
void k_out(const ushort* __restrict__ qkv, const ushort* __restrict__ WtH,
           const float* __restrict__ bias, float* __restrict__ out, int bb0)
{
    __shared__ ushort SM[2 * 128 * GP];
    ushort* Ah = SM;
    ushort* Bh = SM + 128 * GP;
    const int tid = threadIdx.x;
    const int lane = tid & 63, wid = tid >> 6;
    const int ln = lane & 15, lg = lane >> 4;
    const int wm = wid >> 1, wn = wid & 1;
    const int n0 = blockIdx.x * 128, m0 = blockIdx.y * 128;

    const int srow = tid >> 1;
    const int kh = (tid & 1) * 16;
    int mst = m0 + srow;
    int lb = mst >> 8, j0 = mst & 255;
    const ushort* rsrc = qkv + (size_t)(lb * 264 + 8 + j0) * 768;
    const ushort* bsrcH = WtH + (size_t)(n0 + srow) * 256 + kh;

    f32x4 acc[4][4];
#pragma unroll
    for (int i = 0; i < 4; ++i)
#pragma unroll
        for (int j = 0; j < 4; ++j) acc[i][j] = (f32x4){0.f, 0.f, 0.f, 0.f};

    ushort4 apre[4], bpre[4];
#pragma unroll
    for (int j = 0; j < 4; ++j) {
        apre[j] = *(const ushort4*)(rsrc + kh + 4 * j);
        bpre[j] = *(const ushort4*)(bsrcH + 4 * j);
    }

    for (int kt = 0; kt < 256; kt += 32) {
        __syncthreads();
#pragma unroll
        for (int j = 0; j < 4; ++j) {
            *(ushort4*)&Ah[srow * GP + kh + 4 * j] = apre[j];
            *(ushort4*)&Bh[srow * GP + kh + 4 * j] = bpre[j];
        }
        __syncthreads();

        if (kt + 32 < 256) {
#pragma unroll
            for (int j = 0; j < 4; ++j) {
                apre[j] = *(const ushort4*)(rsrc + kt + 32 + kh + 4 * j);
                bpre[j] = *(const ushort4*)(bsrcH + kt + 32 + 4 * j);
            }
        }

        short8 af[4], bf[4];
#pragma unroll
        for (int mi = 0; mi < 4; ++mi) {
            int base = (wm * 64 + mi * 16 + ln) * GP + 4 * lg;
            F8 t;
            t.q[0] = *(const ushort4*)&Ah[base]; t.q[1] = *(const ushort4*)&Ah[base + 16];
            af[mi] = t.v;
        }
#pragma unroll
        for (int ni = 0; ni < 4; ++ni) {
            int base = (wn * 64 + ni * 16 + ln) * GP + 4 * lg;
            F8 t;
            t.q[0] = *(const ushort4*)&Bh[base]; t.q[1] = *(const ushort4*)&Bh[base + 16];
            bf[ni] = t.v;
        }
#pragma unroll
        for (int mi = 0; mi < 4; ++mi)
#pragma unroll
            for (int ni = 0; ni < 4; ++ni)
                acc[mi][ni] = __builtin_amdgcn_mfma_f32_16x16x32_bf16(af[mi], bf[ni], acc[mi][ni], 0, 0, 0);
    }

    float bcol[4];
#pragma unroll
    for (int ni = 0; ni < 4; ++ni) bcol[ni] = bias[n0 + wn * 64 + ni * 16 + ln];

    float* Tr = (float*)SM;
    const int trow = tid >> 3;
    const int tc = (tid & 7) * 4;
#pragma unroll
    for (int mi = 0; mi < 4; ++mi) {
        __syncthreads();
#pragma unroll
        for (int ni = 0; ni < 4; ++ni)
#pragma unroll
            for (int r = 0; r < 4; ++r)
                Tr[(wm * 16 + lg * 4 + r) * 132 + wn * 64 + ni * 16 + ln] = acc[mi][ni][r] + bcol[ni];
        __syncthreads();
        int m = m0 + (trow >> 4) * 64 + mi * 16 + (trow & 15);
        int lb2 = m >> 8, j = m & 255;
        int bb = bb0 + lb2;
        int wn2 = bb & 7, hn = (bb >> 3) & 7, tn = (bb >> 6) & 1, b = bb >> 7;
        int cw = j & 7, ch = (j >> 3) & 7, ct = j >> 6;
        float* dst = out + ((((size_t)(b * 8 + tn * 4 + ct)) * 64 + (hn * 8 + ch)) * 64
                            + (wn2 * 8 + cw)) * 256 + n0;
        const float* src = &Tr[trow * 132];
#pragma unroll
        for (int jj = 0; jj < 4; ++jj)
            *(float4*)(dst + tc + 32 * jj) = *(const float4*)(src + tc + 32 * jj);
    }
}

extern "C" void kernel_launch(void* const* d_in, const int* in_sizes, int n_in,
                              void* d_out, int out_size, void* d_ws, size_t ws_size,
                              hipStream_t stream) {
    const float* x    = (const float*)d_in[0];
    const float* Wqkv = (const float*)d_in[1];
    const float* Wout = (const float*)d_in[2];
    const float* bout = (const float*)d_in[3];
    const float* gtok = (const float*)d_in[4];
    float* out = (float*)d_out;

    ushort* WqtH = (ushort*)d_ws;                        // 768*256 bf16
    ushort* WotH = WqtH + 196608;                        // 256*256 bf16
    ushort* qkv = (ushort*)((char*)d_ws + 1048576);      // bf16: 264*768*2 B/block

    k_prep<<<1024, 256, 0, stream>>>(Wqkv, Wout, WqtH, WotH);

    const size_t per_block = (size_t)264 * 768 * 2;
    int P = (int)((ws_size - 1048576) / per_block);
    if (P > 256) P = 256;
    if (P < 1) P = 1;

    for (int bb0 = 0; bb0 < 256; bb0 += P) {
        int pb = (256 - bb0 < P) ? (256 - bb0) : P;
        int mrows = pb * 264;
        int nb = (mrows + 127) / 128;
        int grid1 = 8 * (((nb + 7) / 8) * 6);
        k_qkv<<<dim3(grid1), 256, 0, stream>>>(x, WqtH, gtok, qkv, nb, bb0, mrows);
        k_attn<<<dim3(pb, 8), 256, 0, stream>>>(qkv);
        k_out<<<dim3(2, pb * 2), 256, 0, stream>>>(qkv, WotH, bout, out, bb0);
    }
}

// Round 21
// 130.415 us; speedup vs baseline: 2.3117x; 2.3117x over previous
//
#include <hip/hip_runtime.h>
#include <math.h>

typedef short short8 __attribute__((ext_vector_type(8)));
typedef float f32x4 __attribute__((ext_vector_type(4)));

static constexpr float SCALE = 0.17677669529663687f; // 32^-0.5

__device__ __forceinline__ ushort f2bf(float x) {
    uint u = __float_as_uint(x);
    u += 0x7fff + ((u >> 16) & 1);
    return (ushort)(u >> 16);
}
__device__ __forceinline__ ushort4 cvt4(float4 v) {
    return make_ushort4(f2bf(v.x), f2bf(v.y), f2bf(v.z), f2bf(v.w));
}

__device__ __forceinline__ const float* row_src(
    int bb, int tok, const float* __restrict__ x, const float* __restrict__ gt)
{
    if (tok < 8) return gt + tok * 256;
    int j = tok - 8;
    int wn = bb & 7, hn = (bb >> 3) & 7, tn = (bb >> 6) & 1, b = bb >> 7;
    int cw = j & 7, ch = (j >> 3) & 7, ct = j >> 6;
    return x + ((((size_t)(b * 8 + tn * 4 + ct)) * 64 + (hn * 8 + ch)) * 64
                + (wn * 8 + cw)) * 256;
}

union F8 { ushort4 q[2]; short8 v; };

// ---------------- K0: transpose weights to [n][k] bf16 ----------------
__global__ __launch_bounds__(256)
void k_prep(const float* __restrict__ Wq, const float* __restrict__ Wo,
            ushort* __restrict__ WqtH, ushort* __restrict__ WotH)
{
    int i = blockIdx.x * 256 + threadIdx.x;
    if (i < 196608) {
        uint k = (uint)i / 768u, n = (uint)i - k * 768u;
        WqtH[n * 256 + k] = f2bf(Wq[i]);
    } else {
        int j = i - 196608;
        uint k = (uint)j >> 8, n = (uint)j & 255u;
        WotH[n * 256 + k] = f2bf(Wo[j]);
    }
}

// ---- K1: QKV GEMM (fp32 gather, bf16 out, XCD swizzle, 2-deep ping-pong) ---
// r18 schedule (measured 76.4 us): pure ds_write between barriers; loads for
// tile it+2 issued after the barrier; cvt after the MFMA block.
#define GP 36
__global__ __launch_bounds__(256, 4)
void k_qkv(const float* __restrict__ x, const ushort* __restrict__ WtH,
           const float* __restrict__ gt, ushort* __restrict__ qkv,
           int nb, int bb0, int mrows)
{
    int g = blockIdx.x;
    int xcd = g & 7;
    int j6 = g >> 3;
    int m_t = (j6 / 6) * 8 + xcd;
    int n_t = j6 % 6;
    if (m_t >= nb) return;
    const int m0 = m_t * 128, n0 = n_t * 128;

    __shared__ ushort SM[2 * 128 * GP];
    ushort* Ah = SM;
    ushort* Bh = SM + 128 * GP;
    const int tid = threadIdx.x;
    const int lane = tid & 63, wid = tid >> 6;
    const int ln = lane & 15, lg = lane >> 4;
    const int wm = wid >> 1, wn = wid & 1;

    const int srow = tid >> 1;
    const int kh = (tid & 1) * 16;
    int mst = m0 + srow;
    if (mst >= mrows) mst = mrows - 1;
    int lb = mst / 264, tok = mst - lb * 264;
    const float* rsrc = row_src(bb0 + lb, tok, x, gt) + kh;
    const ushort* bsrcH = WtH + (size_t)(n0 + srow) * 256 + kh;

    f32x4 acc[4][4];
#pragma unroll
    for (int i = 0; i < 4; ++i)
#pragma unroll
        for (int j = 0; j < 4; ++j) acc[i][j] = (f32x4){0.f, 0.f, 0.f, 0.f};

    ushort4 aset[2][4], bset[2][4];
#pragma unroll
    for (int j = 0; j < 4; ++j) {
        aset[0][j] = cvt4(*(const float4*)(rsrc + 4 * j));
        bset[0][j] = *(const ushort4*)(bsrcH + 4 * j);
        aset[1][j] = cvt4(*(const float4*)(rsrc + 32 + 4 * j));
        bset[1][j] = *(const ushort4*)(bsrcH + 32 + 4 * j);
    }

#pragma unroll
    for (int it = 0; it < 8; ++it) {
        const int s = it & 1;
        __syncthreads();
#pragma unroll
        for (int j = 0; j < 4; ++j) {
            *(ushort4*)&Ah[srow * GP + kh + 4 * j] = aset[s][j];
            *(ushort4*)&Bh[srow * GP + kh + 4 * j] = bset[s][j];
        }
        __syncthreads();

        float4 ta[4];
        ushort4 tb[4];
        const bool more = (it + 2 < 8);
        if (more) {
            const int ktn = 32 * (it + 2);
#pragma unroll
            for (int j = 0; j < 4; ++j) {
                ta[j] = *(const float4*)(rsrc + ktn + 4 * j);
                tb[j] = *(const ushort4*)(bsrcH + ktn + 4 * j);
            }
        }

        short8 af[4], bf[4];
#pragma unroll
        for (int mi = 0; mi < 4; ++mi) {
            int base = (wm * 64 + mi * 16 + ln) * GP + 4 * lg;
            F8 t;
            t.q[0] = *(const ushort4*)&Ah[base]; t.q[1] = *(const ushort4*)&Ah[base + 16];
            af[mi] = t.v;
        }
#pragma unroll
        for (int ni = 0; ni < 4; ++ni) {
            int base = (wn * 64 + ni * 16 + ln) * GP + 4 * lg;
            F8 t;
            t.q[0] = *(const ushort4*)&Bh[base]; t.q[1] = *(const ushort4*)&Bh[base + 16];
            bf[ni] = t.v;
        }
#pragma unroll
        for (int mi = 0; mi < 4; ++mi)
#pragma unroll
            for (int ni = 0; ni < 4; ++ni)
                acc[mi][ni] = __builtin_amdgcn_mfma_f32_16x16x32_bf16(af[mi], bf[ni], acc[mi][ni], 0, 0, 0);

        if (more) {
#pragma unroll
            for (int j = 0; j < 4; ++j) {
                aset[s][j] = cvt4(ta[j]);
                bset[s][j] = tb[j];
            }
        }
    }

    float* Tr = (float*)SM;
    const int trow = tid >> 3;
    const int t8 = (tid & 7) * 8;
#pragma unroll
    for (int mi = 0; mi < 4; ++mi) {
        __syncthreads();
#pragma unroll
        for (int ni = 0; ni < 4; ++ni)
#pragma unroll
            for (int r = 0; r < 4; ++r)
                Tr[(wm * 16 + lg * 4 + r) * 132 + wn * 64 + ni * 16 + ln] = acc[mi][ni][r];
        __syncthreads();
        int gm = m0 + (trow >> 4) * 64 + mi * 16 + (trow & 15);
        if (gm < mrows) {
            ushort* dst = qkv + (size_t)gm * 768 + n0;
            const float* src = &Tr[trow * 132];
#pragma unroll
            for (int half = 0; half < 2; ++half) {
                float4 a = *(const float4*)(src + half * 64 + t8);
                float4 b = *(const float4*)(src + half * 64 + t8 + 4);
                union { ushort4 u4[2]; int4 i4; } pk;
                pk.u4[0] = cvt4(a);
                pk.u4[1] = cvt4(b);
                *(int4*)(dst + half * 64 + t8) = pk.i4;
            }
        }
    }
}

// ---- K2: attention — swapped-operand MFMA, bf16 qkv, NO-MAX softmax --------
#define KPAD 36
#define VPAD 296
__global__ __launch_bounds__(256, 4)
void k_attn(ushort* __restrict__ qkv)
{
    __shared__ ushort Khi[272 * KPAD];
    __shared__ ushort Vt[32 * VPAD];

    const int lb = blockIdx.x, h = blockIdx.y;
    const int tid = threadIdx.x;
    const int wid = tid >> 6;
    const int lane = tid & 63;
    const int ln = lane & 15, lg = lane >> 4;
    ushort* base = qkv + (size_t)lb * (264 * 768);
    const int koff = 256 + h * 32, voff = 512 + h * 32;

    for (int slot = tid; slot < 1056; slot += 256) {
        int rp = slot >> 3;
        int c4 = (slot & 7) * 4;
        int r0 = rp * 2;
        const ushort* p0 = base + (size_t)r0 * 768;
        const ushort* p1 = p0 + 768;
        ushort4 k0 = *(const ushort4*)(p0 + koff + c4);
        ushort4 k1 = *(const ushort4*)(p1 + koff + c4);
        ushort4 v0 = *(const ushort4*)(p0 + voff + c4);
        ushort4 v1 = *(const ushort4*)(p1 + voff + c4);
        *(ushort4*)&Khi[r0 * KPAD + c4] = k0;
        *(ushort4*)&Khi[(r0 + 1) * KPAD + c4] = k1;
        *(ushort2*)&Vt[(c4 + 0) * VPAD + r0] = make_ushort2(v0.x, v1.x);
        *(ushort2*)&Vt[(c4 + 1) * VPAD + r0] = make_ushort2(v0.y, v1.y);
        *(ushort2*)&Vt[(c4 + 2) * VPAD + r0] = make_ushort2(v0.z, v1.z);
        *(ushort2*)&Vt[(c4 + 3) * VPAD + r0] = make_ushort2(v0.w, v1.w);
    }
    for (int slot = tid; slot < 1024; slot += 256) {
        int d = slot >> 5;
        Vt[d * VPAD + 264 + (slot & 31)] = 0;
    }

    short8 qh[4];
#pragma unroll
    for (int t = 0; t < 4; ++t) {
        int qrow = 8 + (wid * 4 + t) * 16 + ln;
        const ushort* qp = base + (size_t)qrow * 768 + h * 32;
        F8 fh;
        fh.q[0] = *(const ushort4*)(qp + 4 * lg);
        fh.q[1] = *(const ushort4*)(qp + 16 + 4 * lg);
        qh[t] = fh.v;
    }

    f32x4 acc[4][2];
    float lsum[4];
#pragma unroll
    for (int t = 0; t < 4; ++t) {
        acc[t][0] = (f32x4){0.f, 0.f, 0.f, 0.f};
        acc[t][1] = (f32x4){0.f, 0.f, 0.f, 0.f};
        lsum[t] = 0.f;
    }

    __syncthreads();

    for (int g = 0; g < 8; ++g) {
        const int kt0 = g * 32;
        F8 fa;
        const ushort* pka = &Khi[(kt0 + ln) * KPAD + 4 * lg];
        fa.q[0] = *(const ushort4*)pka; fa.q[1] = *(const ushort4*)(pka + 16);
        short8 ka = fa.v;
        const ushort* pkb = &Khi[(kt0 + 16 + ln) * KPAD + 4 * lg];
        fa.q[0] = *(const ushort4*)pkb; fa.q[1] = *(const ushort4*)(pkb + 16);
        short8 kb = fa.v;
        const ushort* pv0 = &Vt[ln * VPAD + kt0 + 4 * lg];
        fa.q[0] = *(const ushort4*)pv0; fa.q[1] = *(const ushort4*)(pv0 + 16);
        short8 va = fa.v;
        const ushort* pv1 = &Vt[(16 + ln) * VPAD + kt0 + 4 * lg];
        fa.q[0] = *(const ushort4*)pv1; fa.q[1] = *(const ushort4*)(pv1 + 16);
        short8 vb = fa.v;

#pragma unroll
        for (int t = 0; t < 4; ++t) {
            f32x4 sa = {0.f, 0.f, 0.f, 0.f}, sb = {0.f, 0.f, 0.f, 0.f};
            sa = __builtin_amdgcn_mfma_f32_16x16x32_bf16(ka, qh[t], sa, 0, 0, 0);
            sb = __builtin_amdgcn_mfma_f32_16x16x32_bf16(kb, qh[t], sb, 0, 0, 0);
            float p[8];
#pragma unroll
            for (int c = 0; c < 4; ++c) {
                p[c] = __expf(sa[c] * SCALE);
                p[4 + c] = __expf(sb[c] * SCALE);
            }
            lsum[t] += ((p[0] + p[1]) + (p[2] + p[3])) + ((p[4] + p[5]) + (p[6] + p[7]));
            F8 pf;
            pf.q[0] = make_ushort4(f2bf(p[0]), f2bf(p[1]), f2bf(p[2]), f2bf(p[3]));
            pf.q[1] = make_ushort4(f2bf(p[4]), f2bf(p[5]), f2bf(p[6]), f2bf(p[7]));
            acc[t][0] = __builtin_amdgcn_mfma_f32_16x16x32_bf16(va, pf.v, acc[t][0], 0, 0, 0);
            acc[t][1] = __builtin_amdgcn_mfma_f32_16x16x32_bf16(vb, pf.v, acc[t][1], 0, 0, 0);
        }
    }

    // ---- tail: keys 256..263 (rows >= 8 of the tile masked via lg>=2) ----
    {
        F8 fa;
        const ushort* pka = &Khi[(256 + ln) * KPAD + 4 * lg];
        fa.q[0] = *(const ushort4*)pka; fa.q[1] = *(const ushort4*)(pka + 16);
        short8 ka = fa.v;
        const ushort* pv0 = &Vt[ln * VPAD + 256 + 4 * lg];
        fa.q[0] = *(const ushort4*)pv0; fa.q[1] = *(const ushort4*)(pv0 + 16);
        short8 va = fa.v;
        const ushort* pv1 = &Vt[(16 + ln) * VPAD + 256 + 4 * lg];
        fa.q[0] = *(const ushort4*)pv1; fa.q[1] = *(const ushort4*)(pv1 + 16);
        short8 vb = fa.v;

#pragma unroll
        for (int t = 0; t < 4; ++t) {
            f32x4 sa = {0.f, 0.f, 0.f, 0.f};
            sa = __builtin_amdgcn_mfma_f32_16x16x32_bf16(ka, qh[t], sa, 0, 0, 0);
            float p[4];
#pragma unroll
            for (int c = 0; c < 4; ++c)
                p[c] = (lg >= 2) ? 0.f : __expf(sa[c] * SCALE);
            lsum[t] += (p[0] + p[1]) + (p[2] + p[3]);
            F8 pf;
            pf.q[0] = make_ushort4(f2bf(p[0]), f2bf(p[1]), f2bf(p[2]), f2bf(p[3]));
            pf.q[1] = make_ushort4(0, 0, 0, 0);
            acc[t][0] = __builtin_amdgcn_mfma_f32_16x16x32_bf16(va, pf.v, acc[t][0], 0, 0, 0);
            acc[t][1] = __builtin_amdgcn_mfma_f32_16x16x32_bf16(vb, pf.v, acc[t][1], 0, 0, 0);
        }
    }

#pragma unroll
    for (int t = 0; t < 4; ++t) {
        float l = lsum[t];
        l += __shfl_xor(l, 16);
        l += __shfl_xor(l, 32);
        float inv = 1.f / l;
        ushort* op = base + (size_t)(8 + (wid * 4 + t) * 16 + ln) * 768 + h * 32;
#pragma unroll
        for (int r = 0; r < 4; ++r) {
            op[lg * 4 + r] = f2bf(acc[t][0][r] * inv);
            op[16 + lg * 4 + r] = f2bf(acc[t][1][r] * inv);
        }
    }
}

// ---- K3: output GEMM (bf16 in, simple 2-phase prefetch — r19 form) ---------
__global__ __launch_bounds__(256, 4)
void k_out(const ushort* __restrict__ qkv, const ushort* __restrict__ WtH,
           const float* __restrict__ bias, float* __restrict__ out, int bb0)
{
    __shared__ ushort SM[2 * 128 * GP];
    ushort* Ah = SM;
    ushort* Bh = SM + 128 * GP;
    const int tid = threadIdx.x;
    const int lane = tid & 63, wid = tid >> 6;
    const int ln = lane & 15, lg = lane >> 4;
    const int wm = wid >> 1, wn = wid & 1;
    const int n0 = blockIdx.x * 128, m0 = blockIdx.y * 128;

    const int srow = tid >> 1;
    const int kh = (tid & 1) * 16;
    int mst = m0 + srow;
    int lb = mst >> 8, j0 = mst & 255;
    const ushort* rsrc = qkv + (size_t)(lb * 264 + 8 + j0) * 768;
    const ushort* bsrcH = WtH + (size_t)(n0 + srow) * 256 + kh;

    f32x4 acc[4][4];
#pragma unroll
    for (int i = 0; i < 4; ++i)
#pragma unroll
        for (int j = 0; j < 4; ++j) acc[i][j] = (f32x4){0.f, 0.f, 0.f, 0.f};

    ushort4 apre[4], bpre[4];
#pragma unroll
    for (int j = 0; j < 4; ++j) {
        apre[j] = *(const ushort4*)(rsrc + kh + 4 * j);
        bpre[j] = *(const ushort4*)(bsrcH + 4 * j);
    }

    for (int kt = 0; kt < 256; kt += 32) {
        __syncthreads();
#pragma unroll
        for (int j = 0; j < 4; ++j) {
            *(ushort4*)&Ah[srow * GP + kh + 4 * j] = apre[j];
            *(ushort4*)&Bh[srow * GP + kh + 4 * j] = bpre[j];
        }
        __syncthreads();

        if (kt + 32 < 256) {
#pragma unroll
            for (int j = 0; j < 4; ++j) {
                apre[j] = *(const ushort4*)(rsrc + kt + 32 + kh + 4 * j);
                bpre[j] = *(const ushort4*)(bsrcH + kt + 32 + 4 * j);
            }
        }

        short8 af[4], bf[4];
#pragma unroll
        for (int mi = 0; mi < 4; ++mi) {
            int base = (wm * 64 + mi * 16 + ln) * GP + 4 * lg;
            F8 t;
            t.q[0] = *(const ushort4*)&Ah[base]; t.q[1] = *(const ushort4*)&Ah[base + 16];
            af[mi] = t.v;
        }
#pragma unroll
        for (int ni = 0; ni < 4; ++ni) {
            int base = (wn * 64 + ni * 16 + ln) * GP + 4 * lg;
            F8 t;
            t.q[0] = *(const ushort4*)&Bh[base]; t.q[1] = *(const ushort4*)&Bh[base + 16];
            bf[ni] = t.v;
        }
#pragma unroll
        for (int mi = 0; mi < 4; ++mi)
#pragma unroll
            for (int ni = 0; ni < 4; ++ni)
                acc[mi][ni] = __builtin_amdgcn_mfma_f32_16x16x32_bf16(af[mi], bf[ni], acc[mi][ni], 0, 0, 0);
    }

    float bcol[4];
#pragma unroll
    for (int ni = 0; ni < 4; ++ni) bcol[ni] = bias[n0 + wn * 64 + ni * 16 + ln];

    float* Tr = (float*)SM;
    const int trow = tid >> 3;
    const int tc = (tid & 7) * 4;
#pragma unroll
    for (int mi = 0; mi < 4; ++mi) {
        __syncthreads();
#pragma unroll
        for (int ni = 0; ni < 4; ++ni)
#pragma unroll
            for (int r = 0; r < 4; ++r)
                Tr[(wm * 16 + lg * 4 + r) * 132 + wn * 64 + ni * 16 + ln] = acc[mi][ni][r] + bcol[ni];
        __syncthreads();
        int m = m0 + (trow >> 4) * 64 + mi * 16 + (trow & 15);
        int lb2 = m >> 8, j = m & 255;
        int bb = bb0 + lb2;
        int wn2 = bb & 7, hn = (bb >> 3) & 7, tn = (bb >> 6) & 1, b = bb >> 7;
        int cw = j & 7, ch = (j >> 3) & 7, ct = j >> 6;
        float* dst = out + ((((size_t)(b * 8 + tn * 4 + ct)) * 64 + (hn * 8 + ch)) * 64
                            + (wn2 * 8 + cw)) * 256 + n0;
        const float* src = &Tr[trow * 132];
#pragma unroll
        for (int jj = 0; jj < 4; ++jj)
            *(float4*)(dst + tc + 32 * jj) = *(const float4*)(src + tc + 32 * jj);
    }
}

extern "C" void kernel_launch(void* const* d_in, const int* in_sizes, int n_in,
                              void* d_out, int out_size, void* d_ws, size_t ws_size,
                              hipStream_t stream) {
    const float* x    = (const float*)d_in[0];
    const float* Wqkv = (const float*)d_in[1];
    const float* Wout = (const float*)d_in[2];
    const float* bout = (const float*)d_in[3];
    const float* gtok = (const float*)d_in[4];
    float* out = (float*)d_out;

    ushort* WqtH = (ushort*)d_ws;                        // 768*256 bf16
    ushort* WotH = WqtH + 196608;                        // 256*256 bf16
    ushort* qkv = (ushort*)((char*)d_ws + 1048576);      // bf16: 264*768*2 B/block

    k_prep<<<1024, 256, 0, stream>>>(Wqkv, Wout, WqtH, WotH);

    const size_t per_block = (size_t)264 * 768 * 2;
    int P = (int)((ws_size - 1048576) / per_block);
    if (P > 256) P = 256;
    if (P < 1) P = 1;

    for (int bb0 = 0; bb0 < 256; bb0 += P) {
        int pb = (256 - bb0 < P) ? (256 - bb0) : P;
        int mrows = pb * 264;
        int nb = (mrows + 127) / 128;
        int grid1 = 8 * (((nb + 7) / 8) * 6);
        k_qkv<<<dim3(grid1), 256, 0, stream>>>(x, WqtH, gtok, qkv, nb, bb0, mrows);
        k_attn<<<dim3(pb, 8), 256, 0, stream>>>(qkv);
        k_out<<<dim3(2, pb * 2), 256, 0, stream>>>(qkv, WotH, bout, out, bb0);
    }
}

// Round 22
// 128.081 us; speedup vs baseline: 2.3539x; 1.0182x over previous
//
#include <hip/hip_runtime.h>
#include <math.h>

typedef short short8 __attribute__((ext_vector_type(8)));
typedef float f32x4 __attribute__((ext_vector_type(4)));

static constexpr float SCALE = 0.17677669529663687f; // 32^-0.5

__device__ __forceinline__ ushort f2bf(float x) {
    uint u = __float_as_uint(x);
    u += 0x7fff + ((u >> 16) & 1);
    return (ushort)(u >> 16);
}
__device__ __forceinline__ ushort4 cvt4(float4 v) {
    return make_ushort4(f2bf(v.x), f2bf(v.y), f2bf(v.z), f2bf(v.w));
}

__device__ __forceinline__ const float* row_src(
    int bb, int tok, const float* __restrict__ x, const float* __restrict__ gt)
{
    if (tok < 8) return gt + tok * 256;
    int j = tok - 8;
    int wn = bb & 7, hn = (bb >> 3) & 7, tn = (bb >> 6) & 1, b = bb >> 7;
    int cw = j & 7, ch = (j >> 3) & 7, ct = j >> 6;
    return x + ((((size_t)(b * 8 + tn * 4 + ct)) * 64 + (hn * 8 + ch)) * 64
                + (wn * 8 + cw)) * 256;
}

union F8 { ushort4 q[2]; short8 v; };

// ---------------- K0: transpose weights to [n][k] bf16 ----------------
__global__ __launch_bounds__(256)
void k_prep(const float* __restrict__ Wq, const float* __restrict__ Wo,
            ushort* __restrict__ WqtH, ushort* __restrict__ WotH)
{
    int i = blockIdx.x * 256 + threadIdx.x;
    if (i < 196608) {
        uint k = (uint)i / 768u, n = (uint)i - k * 768u;
        WqtH[n * 256 + k] = f2bf(Wq[i]);
    } else {
        int j = i - 196608;
        uint k = (uint)j >> 8, n = (uint)j & 255u;
        WotH[n * 256 + k] = f2bf(Wo[j]);
    }
}

// ---- K1: QKV GEMM (fp32 gather, bf16 out, XCD swizzle, 2-deep ping-pong) ---
#define GP 36
__global__ __launch_bounds__(256, 4)
void k_qkv(const float* __restrict__ x, const ushort* __restrict__ WtH,
           const float* __restrict__ gt, ushort* __restrict__ qkv,
           int nb, int bb0, int mrows)
{
    int g = blockIdx.x;
    int xcd = g & 7;
    int j6 = g >> 3;
    int m_t = (j6 / 6) * 8 + xcd;
    int n_t = j6 % 6;
    if (m_t >= nb) return;
    const int m0 = m_t * 128, n0 = n_t * 128;

    __shared__ ushort SM[2 * 128 * GP];
    ushort* Ah = SM;
    ushort* Bh = SM + 128 * GP;
    const int tid = threadIdx.x;
    const int lane = tid & 63, wid = tid >> 6;
    const int ln = lane & 15, lg = lane >> 4;
    const int wm = wid >> 1, wn = wid & 1;

    const int srow = tid >> 1;
    const int kh = (tid & 1) * 16;
    int mst = m0 + srow;
    if (mst >= mrows) mst = mrows - 1;
    int lb = mst / 264, tok = mst - lb * 264;
    const float* rsrc = row_src(bb0 + lb, tok, x, gt) + kh;
    const ushort* bsrcH = WtH + (size_t)(n0 + srow) * 256 + kh;

    f32x4 acc[4][4];
#pragma unroll
    for (int i = 0; i < 4; ++i)
#pragma unroll
        for (int j = 0; j < 4; ++j) acc[i][j] = (f32x4){0.f, 0.f, 0.f, 0.f};

    ushort4 aset[2][4], bset[2][4];
#pragma unroll
    for (int j = 0; j < 4; ++j) {
        aset[0][j] = cvt4(*(const float4*)(rsrc + 4 * j));
        bset[0][j] = *(const ushort4*)(bsrcH + 4 * j);
        aset[1][j] = cvt4(*(const float4*)(rsrc + 32 + 4 * j));
        bset[1][j] = *(const ushort4*)(bsrcH + 32 + 4 * j);
    }

#pragma unroll
    for (int it = 0; it < 8; ++it) {
        const int s = it & 1;
        __syncthreads();
#pragma unroll
        for (int j = 0; j < 4; ++j) {
            *(ushort4*)&Ah[srow * GP + kh + 4 * j] = aset[s][j];
            *(ushort4*)&Bh[srow * GP + kh + 4 * j] = bset[s][j];
        }
        __syncthreads();

        float4 ta[4];
        ushort4 tb[4];
        const bool more = (it + 2 < 8);
        if (more) {
            const int ktn = 32 * (it + 2);
#pragma unroll
            for (int j = 0; j < 4; ++j) {
                ta[j] = *(const float4*)(rsrc + ktn + 4 * j);
                tb[j] = *(const ushort4*)(bsrcH + ktn + 4 * j);
            }
        }

        short8 af[4], bf[4];
#pragma unroll
        for (int mi = 0; mi < 4; ++mi) {
            int base = (wm * 64 + mi * 16 + ln) * GP + 4 * lg;
            F8 t;
            t.q[0] = *(const ushort4*)&Ah[base]; t.q[1] = *(const ushort4*)&Ah[base + 16];
            af[mi] = t.v;
        }
#pragma unroll
        for (int ni = 0; ni < 4; ++ni) {
            int base = (wn * 64 + ni * 16 + ln) * GP + 4 * lg;
            F8 t;
            t.q[0] = *(const ushort4*)&Bh[base]; t.q[1] = *(const ushort4*)&Bh[base + 16];
            bf[ni] = t.v;
        }
#pragma unroll
        for (int mi = 0; mi < 4; ++mi)
#pragma unroll
            for (int ni = 0; ni < 4; ++ni)
                acc[mi][ni] = __builtin_amdgcn_mfma_f32_16x16x32_bf16(af[mi], bf[ni], acc[mi][ni], 0, 0, 0);

        if (more) {
#pragma unroll
            for (int j = 0; j < 4; ++j) {
                aset[s][j] = cvt4(ta[j]);
                bset[s][j] = tb[j];
            }
        }
    }

    float* Tr = (float*)SM;
    const int trow = tid >> 3;
    const int t8 = (tid & 7) * 8;
#pragma unroll
    for (int mi = 0; mi < 4; ++mi) {
        __syncthreads();
#pragma unroll
        for (int ni = 0; ni < 4; ++ni)
#pragma unroll
            for (int r = 0; r < 4; ++r)
                Tr[(wm * 16 + lg * 4 + r) * 132 + wn * 64 + ni * 16 + ln] = acc[mi][ni][r];
        __syncthreads();
        int gm = m0 + (trow >> 4) * 64 + mi * 16 + (trow & 15);
        if (gm < mrows) {
            ushort* dst = qkv + (size_t)gm * 768 + n0;
            const float* src = &Tr[trow * 132];
#pragma unroll
            for (int half = 0; half < 2; ++half) {
                float4 a = *(const float4*)(src + half * 64 + t8);
                float4 b = *(const float4*)(src + half * 64 + t8 + 4);
                union { ushort4 u4[2]; int4 i4; } pk;
                pk.u4[0] = cvt4(a);
                pk.u4[1] = cvt4(b);
                *(int4*)(dst + half * 64 + t8) = pk.i4;
            }
        }
    }
}

// ---- K2: attention — swapped MFMA, no-max softmax, XCD-colocated heads -----
// all 8 heads of one cuboid block share g mod 8 -> same XCD L2 (heads share
// 128B cache lines of K/V/Q in pairs).
#define KPAD 36
#define VPAD 296
__global__ __launch_bounds__(256, 4)
void k_attn(ushort* __restrict__ qkv, int pb)
{
    int g = blockIdx.x;
    int xcd = g & 7;
    int j = g >> 3;
    const int lb = (j >> 3) * 8 + xcd;
    const int h = j & 7;
    if (lb >= pb) return;

    __shared__ ushort Khi[272 * KPAD];
    __shared__ ushort Vt[32 * VPAD];

    const int tid = threadIdx.x;
    const int wid = tid >> 6;
    const int lane = tid & 63;
    const int ln = lane & 15, lg = lane >> 4;
    ushort* base = qkv + (size_t)lb * (264 * 768);
    const int koff = 256 + h * 32, voff = 512 + h * 32;

    for (int slot = tid; slot < 1056; slot += 256) {
        int rp = slot >> 3;
        int c4 = (slot & 7) * 4;
        int r0 = rp * 2;
        const ushort* p0 = base + (size_t)r0 * 768;
        const ushort* p1 = p0 + 768;
        ushort4 k0 = *(const ushort4*)(p0 + koff + c4);
        ushort4 k1 = *(const ushort4*)(p1 + koff + c4);
        ushort4 v0 = *(const ushort4*)(p0 + voff + c4);
        ushort4 v1 = *(const ushort4*)(p1 + voff + c4);
        *(ushort4*)&Khi[r0 * KPAD + c4] = k0;
        *(ushort4*)&Khi[(r0 + 1) * KPAD + c4] = k1;
        *(ushort2*)&Vt[(c4 + 0) * VPAD + r0] = make_ushort2(v0.x, v1.x);
        *(ushort2*)&Vt[(c4 + 1) * VPAD + r0] = make_ushort2(v0.y, v1.y);
        *(ushort2*)&Vt[(c4 + 2) * VPAD + r0] = make_ushort2(v0.z, v1.z);
        *(ushort2*)&Vt[(c4 + 3) * VPAD + r0] = make_ushort2(v0.w, v1.w);
    }
    for (int slot = tid; slot < 1024; slot += 256) {
        int d = slot >> 5;
        Vt[d * VPAD + 264 + (slot & 31)] = 0;
    }

    short8 qh[4];
#pragma unroll
    for (int t = 0; t < 4; ++t) {
        int qrow = 8 + (wid * 4 + t) * 16 + ln;
        const ushort* qp = base + (size_t)qrow * 768 + h * 32;
        F8 fh;
        fh.q[0] = *(const ushort4*)(qp + 4 * lg);
        fh.q[1] = *(const ushort4*)(qp + 16 + 4 * lg);
        qh[t] = fh.v;
    }

    f32x4 acc[4][2];
    float lsum[4];
#pragma unroll
    for (int t = 0; t < 4; ++t) {
        acc[t][0] = (f32x4){0.f, 0.f, 0.f, 0.f};
        acc[t][1] = (f32x4){0.f, 0.f, 0.f, 0.f};
        lsum[t] = 0.f;
    }

    __syncthreads();

    for (int gg = 0; gg < 8; ++gg) {
        const int kt0 = gg * 32;
        F8 fa;
        const ushort* pka = &Khi[(kt0 + ln) * KPAD + 4 * lg];
        fa.q[0] = *(const ushort4*)pka; fa.q[1] = *(const ushort4*)(pka + 16);
        short8 ka = fa.v;
        const ushort* pkb = &Khi[(kt0 + 16 + ln) * KPAD + 4 * lg];
        fa.q[0] = *(const ushort4*)pkb; fa.q[1] = *(const ushort4*)(pkb + 16);
        short8 kb = fa.v;
        const ushort* pv0 = &Vt[ln * VPAD + kt0 + 4 * lg];
        fa.q[0] = *(const ushort4*)pv0; fa.q[1] = *(const ushort4*)(pv0 + 16);
        short8 va = fa.v;
        const ushort* pv1 = &Vt[(16 + ln) * VPAD + kt0 + 4 * lg];
        fa.q[0] = *(const ushort4*)pv1; fa.q[1] = *(const ushort4*)(pv1 + 16);
        short8 vb = fa.v;

#pragma unroll
        for (int t = 0; t < 4; ++t) {
            f32x4 sa = {0.f, 0.f, 0.f, 0.f}, sb = {0.f, 0.f, 0.f, 0.f};
            sa = __builtin_amdgcn_mfma_f32_16x16x32_bf16(ka, qh[t], sa, 0, 0, 0);
            sb = __builtin_amdgcn_mfma_f32_16x16x32_bf16(kb, qh[t], sb, 0, 0, 0);
            float p[8];
#pragma unroll
            for (int c = 0; c < 4; ++c) {
                p[c] = __expf(sa[c] * SCALE);
                p[4 + c] = __expf(sb[c] * SCALE);
            }
            lsum[t] += ((p[0] + p[1]) + (p[2] + p[3])) + ((p[4] + p[5]) + (p[6] + p[7]));
            F8 pf;
            pf.q[0] = make_ushort4(f2bf(p[0]), f2bf(p[1]), f2bf(p[2]), f2bf(p[3]));
            pf.q[1] = make_ushort4(f2bf(p[4]), f2bf(p[5]), f2bf(p[6]), f2bf(p[7]));
            acc[t][0] = __builtin_amdgcn_mfma_f32_16x16x32_bf16(va, pf.v, acc[t][0], 0, 0, 0);
            acc[t][1] = __builtin_amdgcn_mfma_f32_16x16x32_bf16(vb, pf.v, acc[t][1], 0, 0, 0);
        }
    }

    // ---- tail: keys 256..263 (rows >= 8 of the tile masked via lg>=2) ----
    {
        F8 fa;
        const ushort* pka = &Khi[(256 + ln) * KPAD + 4 * lg];
        fa.q[0] = *(const ushort4*)pka; fa.q[1] = *(const ushort4*)(pka + 16);
        short8 ka = fa.v;
        const ushort* pv0 = &Vt[ln * VPAD + 256 + 4 * lg];
        fa.q[0] = *(const ushort4*)pv0; fa.q[1] = *(const ushort4*)(pv0 + 16);
        short8 va = fa.v;
        const ushort* pv1 = &Vt[(16 + ln) * VPAD + 256 + 4 * lg];
        fa.q[0] = *(const ushort4*)pv1; fa.q[1] = *(const ushort4*)(pv1 + 16);
        short8 vb = fa.v;

#pragma unroll
        for (int t = 0; t < 4; ++t) {
            f32x4 sa = {0.f, 0.f, 0.f, 0.f};
            sa = __builtin_amdgcn_mfma_f32_16x16x32_bf16(ka, qh[t], sa, 0, 0, 0);
            float p[4];
#pragma unroll
            for (int c = 0; c < 4; ++c)
                p[c] = (lg >= 2) ? 0.f : __expf(sa[c] * SCALE);
            lsum[t] += (p[0] + p[1]) + (p[2] + p[3]);
            F8 pf;
            pf.q[0] = make_ushort4(f2bf(p[0]), f2bf(p[1]), f2bf(p[2]), f2bf(p[3]));
            pf.q[1] = make_ushort4(0, 0, 0, 0);
            acc[t][0] = __builtin_amdgcn_mfma_f32_16x16x32_bf16(va, pf.v, acc[t][0], 0, 0, 0);
            acc[t][1] = __builtin_amdgcn_mfma_f32_16x16x32_bf16(vb, pf.v, acc[t][1], 0, 0, 0);
        }
    }

#pragma unroll
    for (int t = 0; t < 4; ++t) {
        float l = lsum[t];
        l += __shfl_xor(l, 16);
        l += __shfl_xor(l, 32);
        float inv = 1.f / l;
        ushort* op = base + (size_t)(8 + (wid * 4 + t) * 16 + ln) * 768 + h * 32;
#pragma unroll
        for (int r = 0; r < 4; ++r) {
            op[lg * 4 + r] = f2bf(acc[t][0][r] * inv);
            op[16 + lg * 4 + r] = f2bf(acc[t][1][r] * inv);
        }
    }
}

// ---- K3: output GEMM (bf16 in, 2-phase prefetch, XCD-colocated n-tiles) ----
// both n-tiles of one m-tile share g mod 8 -> same XCD L2 (identical A rows).
__global__ __launch_bounds__(256, 4)
void k_out(const ushort* __restrict__ qkv, const ushort* __restrict__ WtH,
           const float* __restrict__ bias, float* __restrict__ out,
           int bb0, int mtiles)
{
    int g = blockIdx.x;
    int xcd = g & 7;
    int j6 = g >> 3;
    const int m_t = (j6 >> 1) * 8 + xcd;
    const int n_t = j6 & 1;
    if (m_t >= mtiles) return;
    const int n0 = n_t * 128, m0 = m_t * 128;

    __shared__ ushort SM[2 * 128 * GP];
    ushort* Ah = SM;
    ushort* Bh = SM + 128 * GP;
    const int tid = threadIdx.x;
    const int lane = tid & 63, wid = tid >> 6;
    const int ln = lane & 15, lg = lane >> 4;
    const int wm = wid >> 1, wn = wid & 1;

    const int srow = tid >> 1;
    const int kh = (tid & 1) * 16;
    int mst = m0 + srow;
    int lb = mst >> 8, j0 = mst & 255;
    const ushort* rsrc = qkv + (size_t)(lb * 264 + 8 + j0) * 768;
    const ushort* bsrcH = WtH + (size_t)(n0 + srow) * 256 + kh;

    f32x4 acc[4][4];
#pragma unroll
    for (int i = 0; i < 4; ++i)
#pragma unroll
        for (int j = 0; j < 4; ++j) acc[i][j] = (f32x4){0.f, 0.f, 0.f, 0.f};

    ushort4 apre[4], bpre[4];
#pragma unroll
    for (int j = 0; j < 4; ++j) {
        apre[j] = *(const ushort4*)(rsrc + kh + 4 * j);
        bpre[j] = *(const ushort4*)(bsrcH + 4 * j);
    }

    for (int kt = 0; kt < 256; kt += 32) {
        __syncthreads();
#pragma unroll
        for (int j = 0; j < 4; ++j) {
            *(ushort4*)&Ah[srow * GP + kh + 4 * j] = apre[j];
            *(ushort4*)&Bh[srow * GP + kh + 4 * j] = bpre[j];
        }
        __syncthreads();

        if (kt + 32 < 256) {
#pragma unroll
            for (int j = 0; j < 4; ++j) {
                apre[j] = *(const ushort4*)(rsrc + kt + 32 + kh + 4 * j);
                bpre[j] = *(const ushort4*)(bsrcH + kt + 32 + 4 * j);
            }
        }

        short8 af[4], bf[4];
#pragma unroll
        for (int mi = 0; mi < 4; ++mi) {
            int base = (wm * 64 + mi * 16 + ln) * GP + 4 * lg;
            F8 t;
            t.q[0] = *(const ushort4*)&Ah[base]; t.q[1] = *(const ushort4*)&Ah[base + 16];
            af[mi] = t.v;
        }
#pragma unroll
        for (int ni = 0; ni < 4; ++ni) {
            int base = (wn * 64 + ni * 16 + ln) * GP + 4 * lg;
            F8 t;
            t.q[0] = *(const ushort4*)&Bh[base]; t.q[1] = *(const ushort4*)&Bh[base + 16];
            bf[ni] = t.v;
        }
#pragma unroll
        for (int mi = 0; mi < 4; ++mi)
#pragma unroll
            for (int ni = 0; ni < 4; ++ni)
                acc[mi][ni] = __builtin_amdgcn_mfma_f32_16x16x32_bf16(af[mi], bf[ni], acc[mi][ni], 0, 0, 0);
    }

    float bcol[4];
#pragma unroll
    for (int ni = 0; ni < 4; ++ni) bcol[ni] = bias[n0 + wn * 64 + ni * 16 + ln];

    float* Tr = (float*)SM;
    const int trow = tid >> 3;
    const int tc = (tid & 7) * 4;
#pragma unroll
    for (int mi = 0; mi < 4; ++mi) {
        __syncthreads();
#pragma unroll
        for (int ni = 0; ni < 4; ++ni)
#pragma unroll
            for (int r = 0; r < 4; ++r)
                Tr[(wm * 16 + lg * 4 + r) * 132 + wn * 64 + ni * 16 + ln] = acc[mi][ni][r] + bcol[ni];
        __syncthreads();
        int m = m0 + (trow >> 4) * 64 + mi * 16 + (trow & 15);
        int lb2 = m >> 8, j = m & 255;
        int bb = bb0 + lb2;
        int wn2 = bb & 7, hn = (bb >> 3) & 7, tn = (bb >> 6) & 1, b = bb >> 7;
        int cw = j & 7, ch = (j >> 3) & 7, ct = j >> 6;
        float* dst = out + ((((size_t)(b * 8 + tn * 4 + ct)) * 64 + (hn * 8 + ch)) * 64
                            + (wn2 * 8 + cw)) * 256 + n0;
        const float* src = &Tr[trow * 132];
#pragma unroll
        for (int jj = 0; jj < 4; ++jj)
            *(float4*)(dst + tc + 32 * jj) = *(const float4*)(src + tc + 32 * jj);
    }
}

extern "C" void kernel_launch(void* const* d_in, const int* in_sizes, int n_in,
                              void* d_out, int out_size, void* d_ws, size_t ws_size,
                              hipStream_t stream) {
    const float* x    = (const float*)d_in[0];
    const float* Wqkv = (const float*)d_in[1];
    const float* Wout = (const float*)d_in[2];
    const float* bout = (const float*)d_in[3];
    const float* gtok = (const float*)d_in[4];
    float* out = (float*)d_out;

    ushort* WqtH = (ushort*)d_ws;                        // 768*256 bf16
    ushort* WotH = WqtH + 196608;                        // 256*256 bf16
    ushort* qkv = (ushort*)((char*)d_ws + 1048576);      // bf16: 264*768*2 B/block

    k_prep<<<1024, 256, 0, stream>>>(Wqkv, Wout, WqtH, WotH);

    const size_t per_block = (size_t)264 * 768 * 2;
    int P = (int)((ws_size - 1048576) / per_block);
    if (P > 256) P = 256;
    if (P < 1) P = 1;

    for (int bb0 = 0; bb0 < 256; bb0 += P) {
        int pb = (256 - bb0 < P) ? (256 - bb0) : P;
        int mrows = pb * 264;
        int nb = (mrows + 127) / 128;
        int grid1 = 8 * (((nb + 7) / 8) * 6);
        int grid2 = 64 * ((pb + 7) / 8);          // 8 xcd x ceil(pb/8) x 8 heads
        int mtiles = pb * 2;
        int grid3 = 16 * ((mtiles + 7) / 8);      // 8 xcd x ceil(M/8) x 2 ntiles
        k_qkv<<<dim3(grid1), 256, 0, stream>>>(x, WqtH, gtok, qkv, nb, bb0, mrows);
        k_attn<<<dim3(grid2), 256, 0, stream>>>(qkv, pb);
        k_out<<<dim3(grid3), 256, 0, stream>>>(qkv, WotH, bout, out, bb0, mtiles);
    }
}

// Round 23
// 127.750 us; speedup vs baseline: 2.3600x; 1.0026x over previous
//
#include <hip/hip_runtime.h>
#include <math.h>

typedef short short8 __attribute__((ext_vector_type(8)));
typedef float f32x4 __attribute__((ext_vector_type(4)));

static constexpr float SCALE = 0.17677669529663687f; // 32^-0.5

__device__ __forceinline__ ushort f2bf(float x) {
    uint u = __float_as_uint(x);
    u += 0x7fff + ((u >> 16) & 1);
    return (ushort)(u >> 16);
}
__device__ __forceinline__ ushort4 cvt4(float4 v) {
    return make_ushort4(f2bf(v.x), f2bf(v.y), f2bf(v.z), f2bf(v.w));
}

__device__ __forceinline__ const float* row_src(
    int bb, int tok, const float* __restrict__ x, const float* __restrict__ gt)
{
    if (tok < 8) return gt + tok * 256;
    int j = tok - 8;
    int wn = bb & 7, hn = (bb >> 3) & 7, tn = (bb >> 6) & 1, b = bb >> 7;
    int cw = j & 7, ch = (j >> 3) & 7, ct = j >> 6;
    return x + ((((size_t)(b * 8 + tn * 4 + ct)) * 64 + (hn * 8 + ch)) * 64
                + (wn * 8 + cw)) * 256;
}

union F8 { ushort4 q[2]; short8 v; };

// ---------------- K0: transpose weights to [n][k] bf16 ----------------
__global__ __launch_bounds__(256)
void k_prep(const float* __restrict__ Wq, const float* __restrict__ Wo,
            ushort* __restrict__ WqtH, ushort* __restrict__ WotH)
{
    int i = blockIdx.x * 256 + threadIdx.x;
    if (i < 196608) {
        uint k = (uint)i / 768u, n = (uint)i - k * 768u;
        WqtH[n * 256 + k] = f2bf(Wq[i]);
    } else {
        int j = i - 196608;
        uint k = (uint)j >> 8, n = (uint)j & 255u;
        WotH[n * 256 + k] = f2bf(Wo[j]);
    }
}

// ---- K1: QKV GEMM (fp32 gather, bf16 out, XCD swizzle, 2-deep ping-pong) ---
// Structural floor: 64 arch-VGPR + 64 acc-AGPR = 128/thread (unified file)
// -> 4 waves/SIMD cap; r18 schedule: pure ds_write between barriers, loads
// for tile it+2 issued post-barrier, cvt after the MFMA block.
#define GP 36
__global__ __launch_bounds__(256, 4)
void k_qkv(const float* __restrict__ x, const ushort* __restrict__ WtH,
           const float* __restrict__ gt, ushort* __restrict__ qkv,
           int nb, int bb0, int mrows)
{
    int g = blockIdx.x;
    int xcd = g & 7;
    int j6 = g >> 3;
    int m_t = (j6 / 6) * 8 + xcd;
    int n_t = j6 % 6;
    if (m_t >= nb) return;
    const int m0 = m_t * 128, n0 = n_t * 128;

    __shared__ ushort SM[2 * 128 * GP];
    ushort* Ah = SM;
    ushort* Bh = SM + 128 * GP;
    const int tid = threadIdx.x;
    const int lane = tid & 63, wid = tid >> 6;
    const int ln = lane & 15, lg = lane >> 4;
    const int wm = wid >> 1, wn = wid & 1;

    const int srow = tid >> 1;
    const int kh = (tid & 1) * 16;
    int mst = m0 + srow;
    if (mst >= mrows) mst = mrows - 1;
    int lb = mst / 264, tok = mst - lb * 264;
    const float* rsrc = row_src(bb0 + lb, tok, x, gt) + kh;
    const ushort* bsrcH = WtH + (size_t)(n0 + srow) * 256 + kh;

    f32x4 acc[4][4];
#pragma unroll
    for (int i = 0; i < 4; ++i)
#pragma unroll
        for (int j = 0; j < 4; ++j) acc[i][j] = (f32x4){0.f, 0.f, 0.f, 0.f};

    ushort4 aset[2][4], bset[2][4];
#pragma unroll
    for (int j = 0; j < 4; ++j) {
        aset[0][j] = cvt4(*(const float4*)(rsrc + 4 * j));
        bset[0][j] = *(const ushort4*)(bsrcH + 4 * j);
        aset[1][j] = cvt4(*(const float4*)(rsrc + 32 + 4 * j));
        bset[1][j] = *(const ushort4*)(bsrcH + 32 + 4 * j);
    }

#pragma unroll
    for (int it = 0; it < 8; ++it) {
        const int s = it & 1;
        __syncthreads();
#pragma unroll
        for (int j = 0; j < 4; ++j) {
            *(ushort4*)&Ah[srow * GP + kh + 4 * j] = aset[s][j];
            *(ushort4*)&Bh[srow * GP + kh + 4 * j] = bset[s][j];
        }
        __syncthreads();

        float4 ta[4];
        ushort4 tb[4];
        const bool more = (it + 2 < 8);
        if (more) {
            const int ktn = 32 * (it + 2);
#pragma unroll
            for (int j = 0; j < 4; ++j) {
                ta[j] = *(const float4*)(rsrc + ktn + 4 * j);
                tb[j] = *(const ushort4*)(bsrcH + ktn + 4 * j);
            }
        }

        short8 af[4], bf[4];
#pragma unroll
        for (int mi = 0; mi < 4; ++mi) {
            int base = (wm * 64 + mi * 16 + ln) * GP + 4 * lg;
            F8 t;
            t.q[0] = *(const ushort4*)&Ah[base]; t.q[1] = *(const ushort4*)&Ah[base + 16];
            af[mi] = t.v;
        }
#pragma unroll
        for (int ni = 0; ni < 4; ++ni) {
            int base = (wn * 64 + ni * 16 + ln) * GP + 4 * lg;
            F8 t;
            t.q[0] = *(const ushort4*)&Bh[base]; t.q[1] = *(const ushort4*)&Bh[base + 16];
            bf[ni] = t.v;
        }
#pragma unroll
        for (int mi = 0; mi < 4; ++mi)
#pragma unroll
            for (int ni = 0; ni < 4; ++ni)
                acc[mi][ni] = __builtin_amdgcn_mfma_f32_16x16x32_bf16(af[mi], bf[ni], acc[mi][ni], 0, 0, 0);

        if (more) {
#pragma unroll
            for (int j = 0; j < 4; ++j) {
                aset[s][j] = cvt4(ta[j]);
                bset[s][j] = tb[j];
            }
        }
    }

    float* Tr = (float*)SM;
    const int trow = tid >> 3;
    const int t8 = (tid & 7) * 8;
#pragma unroll
    for (int mi = 0; mi < 4; ++mi) {
        __syncthreads();
#pragma unroll
        for (int ni = 0; ni < 4; ++ni)
#pragma unroll
            for (int r = 0; r < 4; ++r)
                Tr[(wm * 16 + lg * 4 + r) * 132 + wn * 64 + ni * 16 + ln] = acc[mi][ni][r];
        __syncthreads();
        int gm = m0 + (trow >> 4) * 64 + mi * 16 + (trow & 15);
        if (gm < mrows) {
            ushort* dst = qkv + (size_t)gm * 768 + n0;
            const float* src = &Tr[trow * 132];
#pragma unroll
            for (int half = 0; half < 2; ++half) {
                float4 a = *(const float4*)(src + half * 64 + t8);
                float4 b = *(const float4*)(src + half * 64 + t8 + 4);
                union { ushort4 u4[2]; int4 i4; } pk;
                pk.u4[0] = cvt4(a);
                pk.u4[1] = cvt4(b);
                *(int4*)(dst + half * 64 + t8) = pk.i4;
            }
        }
    }
}

// ---- K2: attention — swapped MFMA, no-max softmax, XCD-colocated heads -----
#define KPAD 36
#define VPAD 296
__global__ __launch_bounds__(256, 4)
void k_attn(ushort* __restrict__ qkv, int pb)
{
    int g = blockIdx.x;
    int xcd = g & 7;
    int j = g >> 3;
    const int lb = (j >> 3) * 8 + xcd;
    const int h = j & 7;
    if (lb >= pb) return;

    __shared__ ushort Khi[272 * KPAD];
    __shared__ ushort Vt[32 * VPAD];

    const int tid = threadIdx.x;
    const int wid = tid >> 6;
    const int lane = tid & 63;
    const int ln = lane & 15, lg = lane >> 4;
    ushort* base = qkv + (size_t)lb * (264 * 768);
    const int koff = 256 + h * 32, voff = 512 + h * 32;

    for (int slot = tid; slot < 1056; slot += 256) {
        int rp = slot >> 3;
        int c4 = (slot & 7) * 4;
        int r0 = rp * 2;
        const ushort* p0 = base + (size_t)r0 * 768;
        const ushort* p1 = p0 + 768;
        ushort4 k0 = *(const ushort4*)(p0 + koff + c4);
        ushort4 k1 = *(const ushort4*)(p1 + koff + c4);
        ushort4 v0 = *(const ushort4*)(p0 + voff + c4);
        ushort4 v1 = *(const ushort4*)(p1 + voff + c4);
        *(ushort4*)&Khi[r0 * KPAD + c4] = k0;
        *(ushort4*)&Khi[(r0 + 1) * KPAD + c4] = k1;
        *(ushort2*)&Vt[(c4 + 0) * VPAD + r0] = make_ushort2(v0.x, v1.x);
        *(ushort2*)&Vt[(c4 + 1) * VPAD + r0] = make_ushort2(v0.y, v1.y);
        *(ushort2*)&Vt[(c4 + 2) * VPAD + r0] = make_ushort2(v0.z, v1.z);
        *(ushort2*)&Vt[(c4 + 3) * VPAD + r0] = make_ushort2(v0.w, v1.w);
    }
    for (int slot = tid; slot < 1024; slot += 256) {
        int d = slot >> 5;
        Vt[d * VPAD + 264 + (slot & 31)] = 0;
    }

    short8 qh[4];
#pragma unroll
    for (int t = 0; t < 4; ++t) {
        int qrow = 8 + (wid * 4 + t) * 16 + ln;
        const ushort* qp = base + (size_t)qrow * 768 + h * 32;
        F8 fh;
        fh.q[0] = *(const ushort4*)(qp + 4 * lg);
        fh.q[1] = *(const ushort4*)(qp + 16 + 4 * lg);
        qh[t] = fh.v;
    }

    f32x4 acc[4][2];
    float lsum[4];
#pragma unroll
    for (int t = 0; t < 4; ++t) {
        acc[t][0] = (f32x4){0.f, 0.f, 0.f, 0.f};
        acc[t][1] = (f32x4){0.f, 0.f, 0.f, 0.f};
        lsum[t] = 0.f;
    }

    __syncthreads();

    for (int gg = 0; gg < 8; ++gg) {
        const int kt0 = gg * 32;
        F8 fa;
        const ushort* pka = &Khi[(kt0 + ln) * KPAD + 4 * lg];
        fa.q[0] = *(const ushort4*)pka; fa.q[1] = *(const ushort4*)(pka + 16);
        short8 ka = fa.v;
        const ushort* pkb = &Khi[(kt0 + 16 + ln) * KPAD + 4 * lg];
        fa.q[0] = *(const ushort4*)pkb; fa.q[1] = *(const ushort4*)(pkb + 16);
        short8 kb = fa.v;
        const ushort* pv0 = &Vt[ln * VPAD + kt0 + 4 * lg];
        fa.q[0] = *(const ushort4*)pv0; fa.q[1] = *(const ushort4*)(pv0 + 16);
        short8 va = fa.v;
        const ushort* pv1 = &Vt[(16 + ln) * VPAD + kt0 + 4 * lg];
        fa.q[0] = *(const ushort4*)pv1; fa.q[1] = *(const ushort4*)(pv1 + 16);
        short8 vb = fa.v;

#pragma unroll
        for (int t = 0; t < 4; ++t) {
            f32x4 sa = {0.f, 0.f, 0.f, 0.f}, sb = {0.f, 0.f, 0.f, 0.f};
            sa = __builtin_amdgcn_mfma_f32_16x16x32_bf16(ka, qh[t], sa, 0, 0, 0);
            sb = __builtin_amdgcn_mfma_f32_16x16x32_bf16(kb, qh[t], sb, 0, 0, 0);
            float p[8];
#pragma unroll
            for (int c = 0; c < 4; ++c) {
                p[c] = __expf(sa[c] * SCALE);
                p[4 + c] = __expf(sb[c] * SCALE);
            }
            lsum[t] += ((p[0] + p[1]) + (p[2] + p[3])) + ((p[4] + p[5]) + (p[6] + p[7]));
            F8 pf;
            pf.q[0] = make_ushort4(f2bf(p[0]), f2bf(p[1]), f2bf(p[2]), f2bf(p[3]));
            pf.q[1] = make_ushort4(f2bf(p[4]), f2bf(p[5]), f2bf(p[6]), f2bf(p[7]));
            acc[t][0] = __builtin_amdgcn_mfma_f32_16x16x32_bf16(va, pf.v, acc[t][0], 0, 0, 0);
            acc[t][1] = __builtin_amdgcn_mfma_f32_16x16x32_bf16(vb, pf.v, acc[t][1], 0, 0, 0);
        }
    }

    // ---- tail: keys 256..263 (rows >= 8 of the tile masked via lg>=2) ----
    {
        F8 fa;
        const ushort* pka = &Khi[(256 + ln) * KPAD + 4 * lg];
        fa.q[0] = *(const ushort4*)pka; fa.q[1] = *(const ushort4*)(pka + 16);
        short8 ka = fa.v;
        const ushort* pv0 = &Vt[ln * VPAD + 256 + 4 * lg];
        fa.q[0] = *(const ushort4*)pv0; fa.q[1] = *(const ushort4*)(pv0 + 16);
        short8 va = fa.v;
        const ushort* pv1 = &Vt[(16 + ln) * VPAD + 256 + 4 * lg];
        fa.q[0] = *(const ushort4*)pv1; fa.q[1] = *(const ushort4*)(pv1 + 16);
        short8 vb = fa.v;

#pragma unroll
        for (int t = 0; t < 4; ++t) {
            f32x4 sa = {0.f, 0.f, 0.f, 0.f};
            sa = __builtin_amdgcn_mfma_f32_16x16x32_bf16(ka, qh[t], sa, 0, 0, 0);
            float p[4];
#pragma unroll
            for (int c = 0; c < 4; ++c)
                p[c] = (lg >= 2) ? 0.f : __expf(sa[c] * SCALE);
            lsum[t] += (p[0] + p[1]) + (p[2] + p[3]);
            F8 pf;
            pf.q[0] = make_ushort4(f2bf(p[0]), f2bf(p[1]), f2bf(p[2]), f2bf(p[3]));
            pf.q[1] = make_ushort4(0, 0, 0, 0);
            acc[t][0] = __builtin_amdgcn_mfma_f32_16x16x32_bf16(va, pf.v, acc[t][0], 0, 0, 0);
            acc[t][1] = __builtin_amdgcn_mfma_f32_16x16x32_bf16(vb, pf.v, acc[t][1], 0, 0, 0);
        }
    }

#pragma unroll
    for (int t = 0; t < 4; ++t) {
        float l = lsum[t];
        l += __shfl_xor(l, 16);
        l += __shfl_xor(l, 32);
        float inv = 1.f / l;
        ushort* op = base + (size_t)(8 + (wid * 4 + t) * 16 + ln) * 768 + h * 32;
#pragma unroll
        for (int r = 0; r < 4; ++r) {
            op[lg * 4 + r] = f2bf(acc[t][0][r] * inv);
            op[16 + lg * 4 + r] = f2bf(acc[t][1][r] * inv);
        }
    }
}

// ---- K3: output GEMM (bf16 in, 2-phase prefetch, XCD-colocated n-tiles) ----
__global__ __launch_bounds__(256, 4)
void k_out(const ushort* __restrict__ qkv, const ushort* __restrict__ WtH,
           const float* __restrict__ bias, float* __restrict__ out,
           int bb0, int mtiles)
{
    int g = blockIdx.x;
    int xcd = g & 7;
    int j6 = g >> 3;
    const int m_t = (j6 >> 1) * 8 + xcd;
    const int n_t = j6 & 1;
    if (m_t >= mtiles) return;
    const int n0 = n_t * 128, m0 = m_t * 128;

    __shared__ ushort SM[2 * 128 * GP];
    ushort* Ah = SM;
    ushort* Bh = SM + 128 * GP;
    const int tid = threadIdx.x;
    const int lane = tid & 63, wid = tid >> 6;
    const int ln = lane & 15, lg = lane >> 4;
    const int wm = wid >> 1, wn = wid & 1;

    const int srow = tid >> 1;
    const int kh = (tid & 1) * 16;
    int mst = m0 + srow;
    int lb = mst >> 8, j0 = mst & 255;
    const ushort* rsrc = qkv + (size_t)(lb * 264 + 8 + j0) * 768;
    const ushort* bsrcH = WtH + (size_t)(n0 + srow) * 256 + kh;

    f32x4 acc[4][4];
#pragma unroll
    for (int i = 0; i < 4; ++i)
#pragma unroll
        for (int j = 0; j < 4; ++j) acc[i][j] = (f32x4){0.f, 0.f, 0.f, 0.f};

    ushort4 apre[4], bpre[4];
#pragma unroll
    for (int j = 0; j < 4; ++j) {
        apre[j] = *(const ushort4*)(rsrc + kh + 4 * j);
        bpre[j] = *(const ushort4*)(bsrcH + 4 * j);
    }

    for (int kt = 0; kt < 256; kt += 32) {
        __syncthreads();
#pragma unroll
        for (int j = 0; j < 4; ++j) {
            *(ushort4*)&Ah[srow * GP + kh + 4 * j] = apre[j];
            *(ushort4*)&Bh[srow * GP + kh + 4 * j] = bpre[j];
        }
        __syncthreads();

        if (kt + 32 < 256) {
#pragma unroll
            for (int j = 0; j < 4; ++j) {
                apre[j] = *(const ushort4*)(rsrc + kt + 32 + kh + 4 * j);
                bpre[j] = *(const ushort4*)(bsrcH + kt + 32 + 4 * j);
            }
        }

        short8 af[4], bf[4];
#pragma unroll
        for (int mi = 0; mi < 4; ++mi) {
            int base = (wm * 64 + mi * 16 + ln) * GP + 4 * lg;
            F8 t;
            t.q[0] = *(const ushort4*)&Ah[base]; t.q[1] = *(const ushort4*)&Ah[base + 16];
            af[mi] = t.v;
        }
#pragma unroll
        for (int ni = 0; ni < 4; ++ni) {
            int base = (wn * 64 + ni * 16 + ln) * GP + 4 * lg;
            F8 t;
            t.q[0] = *(const ushort4*)&Bh[base]; t.q[1] = *(const ushort4*)&Bh[base + 16];
            bf[ni] = t.v;
        }
#pragma unroll
        for (int mi = 0; mi < 4; ++mi)
#pragma unroll
            for (int ni = 0; ni < 4; ++ni)
                acc[mi][ni] = __builtin_amdgcn_mfma_f32_16x16x32_bf16(af[mi], bf[ni], acc[mi][ni], 0, 0, 0);
    }

    float bcol[4];
#pragma unroll
    for (int ni = 0; ni < 4; ++ni) bcol[ni] = bias[n0 + wn * 64 + ni * 16 + ln];

    float* Tr = (float*)SM;
    const int trow = tid >> 3;
    const int tc = (tid & 7) * 4;
#pragma unroll
    for (int mi = 0; mi < 4; ++mi) {
        __syncthreads();
#pragma unroll
        for (int ni = 0; ni < 4; ++ni)
#pragma unroll
            for (int r = 0; r < 4; ++r)
                Tr[(wm * 16 + lg * 4 + r) * 132 + wn * 64 + ni * 16 + ln] = acc[mi][ni][r] + bcol[ni];
        __syncthreads();
        int m = m0 + (trow >> 4) * 64 + mi * 16 + (trow & 15);
        int lb2 = m >> 8, j = m & 255;
        int bb = bb0 + lb2;
        int wn2 = bb & 7, hn = (bb >> 3) & 7, tn = (bb >> 6) & 1, b = bb >> 7;
        int cw = j & 7, ch = (j >> 3) & 7, ct = j >> 6;
        float* dst = out + ((((size_t)(b * 8 + tn * 4 + ct)) * 64 + (hn * 8 + ch)) * 64
                            + (wn2 * 8 + cw)) * 256 + n0;
        const float* src = &Tr[trow * 132];
#pragma unroll
        for (int jj = 0; jj < 4; ++jj)
            *(float4*)(dst + tc + 32 * jj) = *(const float4*)(src + tc + 32 * jj);
    }
}

extern "C" void kernel_launch(void* const* d_in, const int* in_sizes, int n_in,
                              void* d_out, int out_size, void* d_ws, size_t ws_size,
                              hipStream_t stream) {
    const float* x    = (const float*)d_in[0];
    const float* Wqkv = (const float*)d_in[1];
    const float* Wout = (const float*)d_in[2];
    const float* bout = (const float*)d_in[3];
    const float* gtok = (const float*)d_in[4];
    float* out = (float*)d_out;

    ushort* WqtH = (ushort*)d_ws;                        // 768*256 bf16
    ushort* WotH = WqtH + 196608;                        // 256*256 bf16
    ushort* qkv = (ushort*)((char*)d_ws + 1048576);      // bf16: 264*768*2 B/block

    k_prep<<<1024, 256, 0, stream>>>(Wqkv, Wout, WqtH, WotH);

    const size_t per_block = (size_t)264 * 768 * 2;
    int P = (int)((ws_size - 1048576) / per_block);
    if (P > 256) P = 256;
    if (P < 1) P = 1;

    for (int bb0 = 0; bb0 < 256; bb0 += P) {
        int pb = (256 - bb0 < P) ? (256 - bb0) : P;
        int mrows = pb * 264;
        int nb = (mrows + 127) / 128;
        int grid1 = 8 * (((nb + 7) / 8) * 6);
        int grid2 = 64 * ((pb + 7) / 8);          // 8 xcd x ceil(pb/8) x 8 heads
        int mtiles = pb * 2;
        int grid3 = 16 * ((mtiles + 7) / 8);      // 8 xcd x ceil(M/8) x 2 ntiles
        k_qkv<<<dim3(grid1), 256, 0, stream>>>(x, WqtH, gtok, qkv, nb, bb0, mrows);
        k_attn<<<dim3(grid2), 256, 0, stream>>>(qkv, pb);
        k_out<<<dim3(grid3), 256, 0, stream>>>(qkv, WotH, bout, out, bb0, mtiles);
    }
}